// Round 10
// baseline (640.991 us; speedup 1.0000x reference)
//
#include <hip/hip_runtime.h>
#include <hip/hip_bf16.h>

#define NN 50000
#define FIN 256
#define F1 256      // HEADS*HID
#define HEADS 4
#define HID 64
#define NC 40
#define NE 1600000
#define SLOPE 0.2f
#define LOG2E 1.44269504f
#define CHUNK 128
#define NB2 98      // coarse dst buckets (512 nodes each)
#define BSH 9
#define BCAP2 18000 // per-bucket capacity (mean 16327, +13 sigma)
#define TILE 2048   // edges per k_bin block
#define NBLK1 12500 // node blocks per slice in k_agg1s

typedef unsigned int u32;
typedef unsigned short u16;
typedef unsigned char u8;
typedef __attribute__((ext_vector_type(8))) short bf16x8;
typedef __attribute__((ext_vector_type(4))) float f32x4;

__device__ __forceinline__ float us2f(u32 u){ u32 b = u << 16; return __uint_as_float(b); }
__device__ __forceinline__ u16 f2bf(float f){
  u32 b = __float_as_uint(f);
  u32 r = (b + 0x7fffu + ((b >> 16) & 1u)) >> 16;
  return (u16)r;
}
__device__ __forceinline__ int ld_src(const int* ei, int i, int i64){ return i64 ? ei[2*i] : ei[i]; }
__device__ __forceinline__ int ld_dst(const int* ei, int i, int i64){ return i64 ? ei[2*(NE+i)] : ei[NE+i]; }

// ---- int-width detection: flags[1]=1 if edge_index is int64 on device
__global__ void k_detect(const int* ei, int* flags){
  __shared__ int ci;
  if(threadIdx.x==0) ci=0;
  __syncthreads();
  if(ei[2*threadIdx.x+1] != 0) atomicAdd(&ci, 1);
  __syncthreads();
  if(threadIdx.x==0){ flags[0] = 0; flags[1] = (ci == 0) ? 1 : 0; }
}

// ---- streaming prep: x split (blocks 0..6249) + W1 transpose/split (6250..6505)
__global__ __launch_bounds__(256) void k_prep(const float* __restrict__ x, u16* __restrict__ xh, u16* __restrict__ xl,
      const float* __restrict__ W1, u16* __restrict__ w1h, u16* __restrict__ w1l){
  int bid = blockIdx.x, tid = threadIdx.x;
  if(bid < 6250){
    int i = (bid*256 + tid) * 8;
    float4 a = *(const float4*)(x+i);
    float4 b4 = *(const float4*)(x+i+4);
    float v[8] = {a.x,a.y,a.z,a.w,b4.x,b4.y,b4.z,b4.w};
    u16 hi[8], lo[8];
    #pragma unroll
    for(int j=0;j<8;j++){
      u32 u = __float_as_uint(v[j]);
      hi[j] = (u16)(u >> 16);                      // truncate hi
      float hf = __uint_as_float(u & 0xffff0000u);
      lo[j] = (u16)(__float_as_uint(v[j] - hf) >> 16);
    }
    *(ushort4*)&xh[i]   = make_ushort4(hi[0],hi[1],hi[2],hi[3]);
    *(ushort4*)&xh[i+4] = make_ushort4(hi[4],hi[5],hi[6],hi[7]);
    *(ushort4*)&xl[i]   = make_ushort4(lo[0],lo[1],lo[2],lo[3]);
    *(ushort4*)&xl[i+4] = make_ushort4(lo[4],lo[5],lo[6],lo[7]);
  } else {
    int id = (bid-6250)*256 + tid;               // 65536 total
    int n = id & 255, k = id >> 8;
    float v = W1[k*F1 + n];
    u16 h = f2bf(v);
    w1h[n*FIN + k] = h;
    w1l[n*FIN + k] = f2bf(v - us2f(h));
  }
}

// ---- LDS-staged edge binning: dense line-granular bucket appends
__global__ __launch_bounds__(256) void k_bin(const int* __restrict__ ei, const int* __restrict__ flags,
                                             int* __restrict__ cnt, u32* __restrict__ bin){
  __shared__ int hcnt[NB2], hoff[NB2], gbase[NB2], hcur[NB2];
  __shared__ u32 staged[TILE];
  __shared__ u8  sbk[TILE];
  int i64 = flags[1];
  int tid = threadIdx.x;
  int e0 = blockIdx.x * TILE;
  int nn = min(TILE, NE - e0);
  for(int b=tid;b<NB2;b+=256) hcnt[b] = 0;
  __syncthreads();
  u32 val[TILE/256]; int bk[TILE/256];
  #pragma unroll
  for(int j=0;j<TILE/256;j++){
    int t = tid + j*256;
    if(t < nn){
      int i = e0 + t;
      int src = ld_src(ei,i,i64), dst = ld_dst(ei,i,i64);
      bk[j] = dst >> BSH;
      val[j] = (u32)src | ((u32)(dst & 511) << 16);
      atomicAdd(&hcnt[bk[j]], 1);
    } else bk[j] = -1;
  }
  __syncthreads();
  if(tid == 0){
    int run = 0;
    for(int b=0;b<NB2;b++){ hoff[b] = run; hcur[b] = run; run += hcnt[b]; }
  }
  __syncthreads();
  if(tid < NB2 && hcnt[tid] > 0) gbase[tid] = atomicAdd(&cnt[tid], hcnt[tid]);
  __syncthreads();
  #pragma unroll
  for(int j=0;j<TILE/256;j++){
    if(bk[j] >= 0){
      int pos = atomicAdd(&hcur[bk[j]], 1);
      staged[pos] = val[j];
      sbk[pos] = (u8)bk[j];
    }
  }
  __syncthreads();
  for(int s=tid; s<nn; s+=256){
    int b = sbk[s];
    int local = gbase[b] + (s - hoff[b]);
    if(local < BCAP2) bin[(size_t)b*BCAP2 + local] = staged[s];
  }
}

// ---- per-bucket degree histogram + 512-entry LDS exclusive scan
__global__ __launch_bounds__(256) void k_hist(const int* __restrict__ cnt, const u32* __restrict__ bin,
                                              int* __restrict__ rloc, int* __restrict__ bsum){
  __shared__ int dl[512], s1[512], s2[512];
  int b = blockIdx.x, tid = threadIdx.x;
  for(int i=tid;i<512;i+=256) dl[i] = 0;
  __syncthreads();
  int n = min(cnt[b], BCAP2);
  const u32* bp = bin + (size_t)b*BCAP2;
  for(int i=tid;i<n;i+=256) atomicAdd(&dl[(bp[i]>>16)&511], 1);
  __syncthreads();
  for(int i=tid;i<512;i+=256) s1[i] = dl[i];
  __syncthreads();
  int* src = s1; int* dst = s2;
  for(int off=1; off<512; off<<=1){
    for(int i=tid;i<512;i+=256) dst[i] = src[i] + (i>=off ? src[i-off] : 0);
    __syncthreads();
    int* t = src; src = dst; dst = t;
  }
  for(int i=tid;i<512;i+=256) rloc[b*512+i] = src[i] - dl[i];
  if(tid==0) bsum[b] = src[511];
}

// ---- tiny serial scan over 98 bucket totals
__global__ void k_scanb(const int* __restrict__ bsum, int* __restrict__ bbase, int* __restrict__ rowptr){
  if(threadIdx.x==0){
    int run = 0;
    for(int b=0;b<NB2;b++){ bbase[b] = run; run += bsum[b]; }
    rowptr[NN] = run;
  }
}

// ---- per-bucket scatter into contiguous adj window; materializes final rowptr
__global__ __launch_bounds__(256) void k_fill2(const int* __restrict__ cnt, const u32* __restrict__ bin,
                                               const int* __restrict__ rloc, const int* __restrict__ bbase,
                                               int* __restrict__ rowptr, int* __restrict__ adj){
  __shared__ int cur[512];
  int b = blockIdx.x, tid = threadIdx.x;
  int base = bbase[b];
  for(int i=tid;i<512;i+=256){
    int d = b*512 + i;
    int v = base + rloc[b*512+i];
    cur[i] = v;
    if(d < NN) rowptr[d] = v;
  }
  __syncthreads();
  int n = min(cnt[b], BCAP2);
  const u32* bp = bin + (size_t)b*BCAP2;
  for(int i=tid;i<n;i+=256){
    u32 v = bp[i];
    int p = atomicAdd(&cur[(v>>16)&511], 1);
    adj[p] = (int)(v & 0xffffu);
  }
}

// ---- GEMM1 (MFMA bf16x3) + fused attention dots.
__global__ __launch_bounds__(256) void k_gemm1(const short* __restrict__ xh, const short* __restrict__ xl,
                                               const short* __restrict__ wh, const short* __restrict__ wl,
                                               const float* __restrict__ as1, const float* __restrict__ ad1,
                                               u16* __restrict__ h1b,
                                               float* __restrict__ aS, float* __restrict__ aD){
  int w = threadIdx.x >> 6, lane = threadIdx.x & 63;
  int lo = lane & 15, hi = lane >> 4;
  int rowbase = blockIdx.x*64;
  f32x4 acc[4][4];                       // [rg][tt]
  #pragma unroll
  for(int rg=0;rg<4;rg++)
    #pragma unroll
    for(int tt=0;tt<4;tt++) acc[rg][tt] = (f32x4){0.f,0.f,0.f,0.f};
  size_t aoff[4];
  #pragma unroll
  for(int rg=0;rg<4;rg++){
    int r = rowbase + rg*16 + lo; if(r >= NN) r = NN-1;
    aoff[rg] = (size_t)r*FIN + 8*hi;
  }
  const short* wph = wh + (size_t)(w*64+lo)*FIN + 8*hi;
  const short* wpl = wl + (size_t)(w*64+lo)*FIN + 8*hi;
  for(int k0=0; k0<FIN; k0+=32){
    bf16x8 ah[4], al[4], bh[4], bl[4];
    #pragma unroll
    for(int rg=0;rg<4;rg++){
      ah[rg] = *(const bf16x8*)(xh + aoff[rg] + k0);
      al[rg] = *(const bf16x8*)(xl + aoff[rg] + k0);
    }
    #pragma unroll
    for(int tt=0;tt<4;tt++){
      bh[tt] = *(const bf16x8*)(wph + (size_t)tt*16*FIN + k0);
      bl[tt] = *(const bf16x8*)(wpl + (size_t)tt*16*FIN + k0);
    }
    #pragma unroll
    for(int rg=0;rg<4;rg++){
      #pragma unroll
      for(int tt=0;tt<4;tt++){
        acc[rg][tt] = __builtin_amdgcn_mfma_f32_16x16x32_bf16(ah[rg], bh[tt], acc[rg][tt], 0, 0, 0);
        acc[rg][tt] = __builtin_amdgcn_mfma_f32_16x16x32_bf16(al[rg], bh[tt], acc[rg][tt], 0, 0, 0);
        acc[rg][tt] = __builtin_amdgcn_mfma_f32_16x16x32_bf16(ah[rg], bl[tt], acc[rg][tt], 0, 0, 0);
      }
    }
  }
  #pragma unroll
  for(int rg=0;rg<4;rg++){
    #pragma unroll
    for(int tt=0;tt<4;tt++){
      #pragma unroll
      for(int r=0;r<4;r++){
        int row = rowbase + rg*16 + hi*4 + r;
        if(row < NN) h1b[(size_t)row*F1 + w*64 + tt*16 + lo] = f2bf(acc[rg][tt][r]);
      }
    }
  }
  // fused attention dots for head w (prescaled by log2 e)
  float ps[4][4], pd[4][4];              // [rg][r]
  #pragma unroll
  for(int rg=0;rg<4;rg++)
    #pragma unroll
    for(int r=0;r<4;r++){ ps[rg][r]=0.f; pd[rg][r]=0.f; }
  #pragma unroll
  for(int tt=0;tt<4;tt++){
    float sv = as1[w*64+tt*16+lo]*LOG2E, dv = ad1[w*64+tt*16+lo]*LOG2E;
    #pragma unroll
    for(int rg=0;rg<4;rg++)
      #pragma unroll
      for(int r=0;r<4;r++){ ps[rg][r] += acc[rg][tt][r]*sv; pd[rg][r] += acc[rg][tt][r]*dv; }
  }
  #pragma unroll
  for(int off=1; off<16; off<<=1){
    #pragma unroll
    for(int rg=0;rg<4;rg++)
      #pragma unroll
      for(int r=0;r<4;r++){
        ps[rg][r] += __shfl_xor(ps[rg][r], off, 64);
        pd[rg][r] += __shfl_xor(pd[rg][r], off, 64);
      }
  }
  if(lo == 0){
    #pragma unroll
    for(int rg=0;rg<4;rg++)
      #pragma unroll
      for(int r=0;r<4;r++){
        int row = rowbase + rg*16 + hi*4 + r;
        if(row < NN){ aS[row*HEADS+w] = ps[rg][r]; aD[row*HEADS+w] = pd[rg][r]; }
      }
  }
}

// ---- layer-1 aggregation, feature-sliced: slice = bid/NBLK1 (32 ch, 3.2MB -> per-XCD L2-resident).
// Wave per node per slice. Phase A recomputes per-edge weight for this slice's head (cheap, L2-hot);
// phase B gathers one 64B line per edge (16 lanes x 4B), 4 edges in flight per wave.
__global__ __launch_bounds__(256) void k_agg1s(const u16* __restrict__ h1b,
  const float* __restrict__ aS, const float* __restrict__ aD,
  const int* __restrict__ rowptr, const int* __restrict__ adj,
  const float* __restrict__ b1, const float* __restrict__ g1, const float* __restrict__ be1,
  const float* __restrict__ mn1, const float* __restrict__ vr1,
  float* __restrict__ h2){
  __shared__ int   lsrc[4][CHUNK];
  __shared__ float lw[4][CHUNK];
  int w = threadIdx.x >> 6, lane = threadIdx.x & 63;
  int s = blockIdx.x / NBLK1;            // slice 0..7 (slow-varying -> co-resident blocks share slice)
  int nb = blockIdx.x % NBLK1;
  int node = nb*4 + w;
  int h = s >> 1;                        // head of this slice
  int chan0 = s * 32;
  int g = lane >> 4, li = lane & 15;
  int beg = rowptr[node], end = rowptr[node+1];
  float adh = aD[node*HEADS + h];
  float den = 0.f, acc0 = 0.f, acc1 = 0.f;
  int total = end - beg + 1;             // + self loop
  for(int c0=0; c0<total; c0+=CHUNK){
    int n = min(CHUNK, total - c0);
    for(int i=lane; i<n; i+=64){
      int e = beg + c0 + i;
      int src = (e < end) ? adj[e] : node;
      float ev = aS[src*HEADS + h] + adh;
      ev = ev > 0.f ? ev : SLOPE*ev;
      float wg = exp2f(fminf(ev, 110.f));
      lsrc[w][i] = src;
      lw[w][i] = wg;
      den += wg;
    }
    asm volatile("s_waitcnt lgkmcnt(0)" ::: "memory");
    for(int i=0; i<n; i+=4){
      int e = i + g;
      bool ok = e < n;
      int src = ok ? lsrc[w][e] : node;
      float wg = ok ? lw[w][e] : 0.f;
      u32 pv = *(const u32*)&h1b[(size_t)src*F1 + chan0 + li*2];
      acc0 += wg*us2f(pv & 0xffffu);
      acc1 += wg*us2f(pv >> 16);
    }
  }
  #pragma unroll
  for(int off=1; off<64; off<<=1) den += __shfl_xor(den, off, 64);
  acc0 += __shfl_xor(acc0, 16, 64); acc0 += __shfl_xor(acc0, 32, 64);
  acc1 += __shfl_xor(acc1, 16, 64); acc1 += __shfl_xor(acc1, 32, 64);
  if(g == 0){
    float inv = 1.f/(den + 1e-16f);
    int c = chan0 + li*2;
    float v0 = acc0*inv + b1[c];
    v0 = (v0 - mn1[c]) * rsqrtf(vr1[c] + 1e-5f) * g1[c] + be1[c];
    v0 = v0 > 0.f ? v0 : (__expf(v0) - 1.f);
    float v1 = acc1*inv + b1[c+1];
    v1 = (v1 - mn1[c+1]) * rsqrtf(vr1[c+1] + 1e-5f) * g1[c+1] + be1[c+1];
    v1 = v1 > 0.f ? v1 : (__expf(v1) - 1.f);
    *(float2*)&h2[(size_t)node*F1 + c] = make_float2(v0, v1);
  }
}

// ---- GEMM2 (8 waves/block) + attention dots layer 2 (prescaled)
__global__ __launch_bounds__(512) void k_gemm2(const float* __restrict__ h2, const float* __restrict__ W2,
    const float* __restrict__ as2, const float* __restrict__ ad2,
    float* __restrict__ h2p, float* __restrict__ aS2, float* __restrict__ aD2){
  __shared__ float w2s[F1*NC];          // 40 KB
  __shared__ float sh2[8][F1];          // 8 KB
  for(int i=threadIdx.x; i<F1*NC; i+=512) w2s[i] = W2[i];
  int w = threadIdx.x >> 6, lane = threadIdx.x & 63;
  int node = blockIdx.x*8 + w;
  {
    float4 hv = *(const float4*)&h2[(size_t)node*F1 + lane*4];
    *(float4*)&sh2[w][lane*4] = hv;
  }
  __syncthreads();
  float acc = 0.f;
  if(lane < NC){
    #pragma unroll 8
    for(int k=0; k<F1; k++) acc += sh2[w][k] * w2s[k*NC + lane];
  }
  float av = (lane < NC) ? as2[lane] : 0.f;
  float dv = (lane < NC) ? ad2[lane] : 0.f;
  float ps = acc*av, pd = acc*dv;
  #pragma unroll
  for(int off=1; off<64; off<<=1){ ps += __shfl_xor(ps,off,64); pd += __shfl_xor(pd,off,64); }
  if(lane < NC) h2p[(size_t)node*NC + lane] = acc;
  if(lane == 0){ aS2[node] = ps*LOG2E; aD2[node] = pd*LOG2E; }
}

// ---- layer-2 aggregation -> output (f32), no max pass, LDS weights
__global__ __launch_bounds__(256) void k_agg2(const float* __restrict__ h2p,
  const float* __restrict__ aS2, const float* __restrict__ aD2,
  const int* __restrict__ rowptr, const int* __restrict__ adj,
  const float* __restrict__ b2, float* __restrict__ out){
  __shared__ float lw[4][CHUNK];
  __shared__ int   lsrc[4][CHUNK];
  int w = threadIdx.x >> 6, lane = threadIdx.x & 63;
  int node = blockIdx.x*4 + w;
  int beg = rowptr[node], end = rowptr[node+1];
  float adv = aD2[node];
  float den = 0.f, acc = 0.f;
  int total = end - beg + 1;
  for(int c0=0; c0<total; c0+=CHUNK){
    int n = min(CHUNK, total - c0);
    for(int i=lane; i<n; i+=64){
      int e = beg + c0 + i;
      int src = (e < end) ? adj[e] : node;
      float ev = aS2[src] + adv; ev = ev>0.f?ev:SLOPE*ev;
      float wg = exp2f(fminf(ev,110.f));
      lsrc[w][i] = src;
      lw[w][i] = wg;
      den += wg;
    }
    asm volatile("s_waitcnt lgkmcnt(0)" ::: "memory");
    #pragma unroll 2
    for(int i=0;i<n;i++){
      int s = lsrc[w][i];
      float wg = lw[w][i];
      if(lane < NC) acc += wg * h2p[(size_t)s*NC + lane];
    }
  }
  #pragma unroll
  for(int off=1; off<64; off<<=1) den += __shfl_xor(den, off, 64);
  if(lane < NC) out[(size_t)node*NC + lane] = acc/(den + 1e-16f) + b2[lane];
}

extern "C" void kernel_launch(void* const* d_in, const int* in_sizes, int n_in,
                              void* d_out, int out_size, void* d_ws, size_t ws_size,
                              hipStream_t stream){
  (void)in_sizes; (void)n_in; (void)out_size; (void)ws_size;
  const float* x   = (const float*)d_in[0];
  const int*   ei  = (const int*)d_in[1];
  const float* W1  = (const float*)d_in[2];
  const float* as1 = (const float*)d_in[3];
  const float* ad1 = (const float*)d_in[4];
  const float* b1  = (const float*)d_in[5];
  const float* g1  = (const float*)d_in[6];
  const float* be1 = (const float*)d_in[7];
  const float* mn1 = (const float*)d_in[8];
  const float* vr1 = (const float*)d_in[9];
  const float* W2  = (const float*)d_in[10];
  const float* as2 = (const float*)d_in[11];
  const float* ad2 = (const float*)d_in[12];
  const float* b2  = (const float*)d_in[13];

  char* ws = (char*)d_ws;
  u16*  h1b    = (u16*) (ws + 0);             // 25,600,000 (bf16 h1)
  float* h2    = (float*)(ws + 25600000);     // 51,200,000
  // xh/xl alias h2 (dead once k_gemm1 completes; h2 written later by k_agg1s)
  u16*  xh     = (u16*) (ws + 25600000);      // 25,600,000
  u16*  xl     = (u16*) (ws + 51200000);      // 25,600,000
  // w1h/w1l alias h2p (dead before k_gemm2 writes h2p)
  float* h2p   = (float*)(ws + 76800000);     //  8,000,000
  u16*  w1h    = (u16*) (ws + 76800000);      //    131,072
  u16*  w1l    = (u16*) (ws + 76931072);      //    131,072
  float* aS1   = (float*)(ws + 84800000);     //    800,000
  float* aD1   = (float*)(ws + 85600000);     //    800,000
  float* aS2   = (float*)(ws + 86400000);     //    200,000
  float* aD2   = (float*)(ws + 86600000);     //    200,000
  int*  rowptr = (int*)  (ws + 86800000);     //    200,016
  int*  adj    = (int*)  (ws + 87200016);     //  6,400,000
  int*  flags  = (int*)  (ws + 93600016);     //         16
  u32*  bin    = (u32*)  (ws + 93700000);     //  7,056,000 (98*18000*4)
  int*  cnt    = (int*)  (ws + 100800000);    //        392 (98*4)
  int*  rloc   = (int*)  (ws + 100801024);    //    200,704 (98*512*4)
  int*  bsum   = (int*)  (ws + 101002240);    //        392
  int*  bbase  = (int*)  (ws + 101003264);    //        392

  hipMemsetAsync(cnt, 0, NB2*sizeof(int), stream);
  k_detect<<<1, 256, 0, stream>>>(ei, flags);
  k_prep  <<<6506, 256, 0, stream>>>(x, xh, xl, W1, w1h, w1l);
  k_bin   <<<(NE+TILE-1)/TILE, 256, 0, stream>>>(ei, flags, cnt, bin);
  k_hist  <<<NB2, 256, 0, stream>>>(cnt, bin, rloc, bsum);
  k_scanb <<<1, 64, 0, stream>>>(bsum, bbase, rowptr);
  k_fill2 <<<NB2, 256, 0, stream>>>(cnt, bin, rloc, bbase, rowptr, adj);
  k_gemm1 <<<(NN+63)/64, 256, 0, stream>>>((const short*)xh, (const short*)xl,
                                           (const short*)w1h, (const short*)w1l,
                                           as1, ad1, h1b, aS1, aD1);
  k_agg1s <<<8*NBLK1, 256, 0, stream>>>(h1b, aS1, aD1, rowptr, adj, b1, g1, be1, mn1, vr1, h2);
  k_gemm2 <<<NN/8, 512, 0, stream>>>(h2, W2, as2, ad2, h2p, aS2, aD2);
  k_agg2  <<<NN/4, 256, 0, stream>>>(h2p, aS2, aD2, rowptr, adj, b2, (float*)d_out);
}

// Round 11
// 409.413 us; speedup vs baseline: 1.5656x; 1.5656x over previous
//
#include <hip/hip_runtime.h>
#include <hip/hip_bf16.h>

#define NN 50000
#define FIN 256
#define F1 256      // HEADS*HID
#define HEADS 4
#define HID 64
#define NC 40
#define NE 1600000
#define SLOPE 0.2f
#define LOG2E 1.44269504f
#define CHUNK 128
#define NB2 98      // coarse dst buckets (512 nodes each)
#define BSH 9
#define BCAP2 18000 // per-bucket capacity (mean 16327, +13 sigma)
#define TILE 2048   // edges per k_bin block

typedef unsigned int u32;
typedef unsigned short u16;
typedef unsigned char u8;
typedef __attribute__((ext_vector_type(8))) short bf16x8;
typedef __attribute__((ext_vector_type(4))) float f32x4;

__device__ __forceinline__ float us2f(u32 u){ u32 b = u << 16; return __uint_as_float(b); }
__device__ __forceinline__ u16 f2bf(float f){
  u32 b = __float_as_uint(f);
  u32 r = (b + 0x7fffu + ((b >> 16) & 1u)) >> 16;
  return (u16)r;
}

// ---- streaming prep: x split (0..6249) + W1 transpose/split (6250..6505) + W2 transpose/split (6506..6553)
__global__ __launch_bounds__(256) void k_prep(const float* __restrict__ x, u16* __restrict__ xh, u16* __restrict__ xl,
      const float* __restrict__ W1, u16* __restrict__ w1h, u16* __restrict__ w1l,
      const float* __restrict__ W2, u16* __restrict__ w2h, u16* __restrict__ w2l){
  int bid = blockIdx.x, tid = threadIdx.x;
  if(bid < 6250){
    int i = (bid*256 + tid) * 8;
    float4 a = *(const float4*)(x+i);
    float4 b4 = *(const float4*)(x+i+4);
    float v[8] = {a.x,a.y,a.z,a.w,b4.x,b4.y,b4.z,b4.w};
    u16 hi[8], lo[8];
    #pragma unroll
    for(int j=0;j<8;j++){
      u32 u = __float_as_uint(v[j]);
      hi[j] = (u16)(u >> 16);                      // truncate hi
      float hf = __uint_as_float(u & 0xffff0000u);
      lo[j] = (u16)(__float_as_uint(v[j] - hf) >> 16);
    }
    *(ushort4*)&xh[i]   = make_ushort4(hi[0],hi[1],hi[2],hi[3]);
    *(ushort4*)&xh[i+4] = make_ushort4(hi[4],hi[5],hi[6],hi[7]);
    *(ushort4*)&xl[i]   = make_ushort4(lo[0],lo[1],lo[2],lo[3]);
    *(ushort4*)&xl[i+4] = make_ushort4(lo[4],lo[5],lo[6],lo[7]);
  } else if(bid < 6506){
    int id = (bid-6250)*256 + tid;               // 65536 total
    int n = id & 255, k = id >> 8;
    float v = W1[k*F1 + n];
    u16 h = f2bf(v);
    w1h[n*FIN + k] = h;
    w1l[n*FIN + k] = f2bf(v - us2f(h));
  } else {
    int id = (bid-6506)*256 + tid;               // 12288 total: col 0..47, k 0..255
    int col = id >> 8, k = id & 255;
    float v = (col < NC) ? W2[k*NC + col] : 0.f;
    u16 h = f2bf(v);
    w2h[col*F1 + k] = h;
    w2l[col*F1 + k] = f2bf(v - us2f(h));
  }
}

// ---- LDS-staged edge binning (int-width detection inlined per tile)
__global__ __launch_bounds__(256) void k_bin(const int* __restrict__ ei,
                                             int* __restrict__ cnt, u32* __restrict__ bin){
  __shared__ int hcnt[NB2], hoff[NB2], gbase[NB2], hcur[NB2];
  __shared__ u32 staged[TILE];
  __shared__ u8  sbk[TILE];
  __shared__ int ci;
  int tid = threadIdx.x;
  int e0 = blockIdx.x * TILE;
  int nn = min(TILE, NE - e0);
  if(tid==0) ci = 0;
  for(int b=tid;b<NB2;b+=256) hcnt[b] = 0;
  __syncthreads();
  if(ei[2*(e0+tid)+1] != 0) atomicAdd(&ci, 1);   // int64: odd words all 0; int32: ~all nonzero
  __syncthreads();
  int i64 = (ci == 0);
  u32 val[TILE/256]; int bk[TILE/256];
  #pragma unroll
  for(int j=0;j<TILE/256;j++){
    int t = tid + j*256;
    if(t < nn){
      int i = e0 + t;
      int src = i64 ? ei[2*i] : ei[i];
      int dst = i64 ? ei[2*(NE+i)] : ei[NE+i];
      bk[j] = dst >> BSH;
      val[j] = (u32)src | ((u32)(dst & 511) << 16);
      atomicAdd(&hcnt[bk[j]], 1);
    } else bk[j] = -1;
  }
  __syncthreads();
  if(tid == 0){
    int run = 0;
    for(int b=0;b<NB2;b++){ hoff[b] = run; hcur[b] = run; run += hcnt[b]; }
  }
  __syncthreads();
  if(tid < NB2 && hcnt[tid] > 0) gbase[tid] = atomicAdd(&cnt[tid], hcnt[tid]);
  __syncthreads();
  #pragma unroll
  for(int j=0;j<TILE/256;j++){
    if(bk[j] >= 0){
      int pos = atomicAdd(&hcur[bk[j]], 1);
      staged[pos] = val[j];
      sbk[pos] = (u8)bk[j];
    }
  }
  __syncthreads();
  for(int s=tid; s<nn; s+=256){
    int b = sbk[s];
    int local = gbase[b] + (s - hoff[b]);
    if(local < BCAP2) bin[(size_t)b*BCAP2 + local] = staged[s];
  }
}

// ---- per-bucket degree histogram + 512-entry LDS exclusive scan
__global__ __launch_bounds__(256) void k_hist(const int* __restrict__ cnt, const u32* __restrict__ bin,
                                              int* __restrict__ rloc, int* __restrict__ bsum){
  __shared__ int dl[512], s1[512], s2[512];
  int b = blockIdx.x, tid = threadIdx.x;
  for(int i=tid;i<512;i+=256) dl[i] = 0;
  __syncthreads();
  int n = min(cnt[b], BCAP2);
  const u32* bp = bin + (size_t)b*BCAP2;
  for(int i=tid;i<n;i+=256) atomicAdd(&dl[(bp[i]>>16)&511], 1);
  __syncthreads();
  for(int i=tid;i<512;i+=256) s1[i] = dl[i];
  __syncthreads();
  int* src = s1; int* dst = s2;
  for(int off=1; off<512; off<<=1){
    for(int i=tid;i<512;i+=256) dst[i] = src[i] + (i>=off ? src[i-off] : 0);
    __syncthreads();
    int* t = src; src = dst; dst = t;
  }
  for(int i=tid;i<512;i+=256) rloc[b*512+i] = src[i] - dl[i];
  if(tid==0) bsum[b] = src[511];
}

// ---- tiny serial scan over 98 bucket totals
__global__ void k_scanb(const int* __restrict__ bsum, int* __restrict__ bbase, int* __restrict__ rowptr){
  if(threadIdx.x==0){
    int run = 0;
    for(int b=0;b<NB2;b++){ bbase[b] = run; run += bsum[b]; }
    rowptr[NN] = run;
  }
}

// ---- per-bucket scatter into contiguous adj window; materializes final rowptr
__global__ __launch_bounds__(256) void k_fill2(const int* __restrict__ cnt, const u32* __restrict__ bin,
                                               const int* __restrict__ rloc, const int* __restrict__ bbase,
                                               int* __restrict__ rowptr, int* __restrict__ adj){
  __shared__ int cur[512];
  int b = blockIdx.x, tid = threadIdx.x;
  int base = bbase[b];
  for(int i=tid;i<512;i+=256){
    int d = b*512 + i;
    int v = base + rloc[b*512+i];
    cur[i] = v;
    if(d < NN) rowptr[d] = v;
  }
  __syncthreads();
  int n = min(cnt[b], BCAP2);
  const u32* bp = bin + (size_t)b*BCAP2;
  for(int i=tid;i<n;i+=256){
    u32 v = bp[i];
    int p = atomicAdd(&cur[(v>>16)&511], 1);
    adj[p] = (int)(v & 0xffffu);
  }
}

// ---- GEMM1 (MFMA bf16x3) + fused attention dots.
__global__ __launch_bounds__(256) void k_gemm1(const short* __restrict__ xh, const short* __restrict__ xl,
                                               const short* __restrict__ wh, const short* __restrict__ wl,
                                               const float* __restrict__ as1, const float* __restrict__ ad1,
                                               u16* __restrict__ h1b,
                                               float* __restrict__ aS, float* __restrict__ aD){
  int w = threadIdx.x >> 6, lane = threadIdx.x & 63;
  int lo = lane & 15, hi = lane >> 4;
  int rowbase = blockIdx.x*64;
  f32x4 acc[4][4];                       // [rg][tt]
  #pragma unroll
  for(int rg=0;rg<4;rg++)
    #pragma unroll
    for(int tt=0;tt<4;tt++) acc[rg][tt] = (f32x4){0.f,0.f,0.f,0.f};
  size_t aoff[4];
  #pragma unroll
  for(int rg=0;rg<4;rg++){
    int r = rowbase + rg*16 + lo; if(r >= NN) r = NN-1;
    aoff[rg] = (size_t)r*FIN + 8*hi;
  }
  const short* wph = wh + (size_t)(w*64+lo)*FIN + 8*hi;
  const short* wpl = wl + (size_t)(w*64+lo)*FIN + 8*hi;
  for(int k0=0; k0<FIN; k0+=32){
    bf16x8 ah[4], al[4], bh[4], bl[4];
    #pragma unroll
    for(int rg=0;rg<4;rg++){
      ah[rg] = *(const bf16x8*)(xh + aoff[rg] + k0);
      al[rg] = *(const bf16x8*)(xl + aoff[rg] + k0);
    }
    #pragma unroll
    for(int tt=0;tt<4;tt++){
      bh[tt] = *(const bf16x8*)(wph + (size_t)tt*16*FIN + k0);
      bl[tt] = *(const bf16x8*)(wpl + (size_t)tt*16*FIN + k0);
    }
    #pragma unroll
    for(int rg=0;rg<4;rg++){
      #pragma unroll
      for(int tt=0;tt<4;tt++){
        acc[rg][tt] = __builtin_amdgcn_mfma_f32_16x16x32_bf16(ah[rg], bh[tt], acc[rg][tt], 0, 0, 0);
        acc[rg][tt] = __builtin_amdgcn_mfma_f32_16x16x32_bf16(al[rg], bh[tt], acc[rg][tt], 0, 0, 0);
        acc[rg][tt] = __builtin_amdgcn_mfma_f32_16x16x32_bf16(ah[rg], bl[tt], acc[rg][tt], 0, 0, 0);
      }
    }
  }
  #pragma unroll
  for(int rg=0;rg<4;rg++){
    #pragma unroll
    for(int tt=0;tt<4;tt++){
      #pragma unroll
      for(int r=0;r<4;r++){
        int row = rowbase + rg*16 + hi*4 + r;
        if(row < NN) h1b[(size_t)row*F1 + w*64 + tt*16 + lo] = f2bf(acc[rg][tt][r]);
      }
    }
  }
  // fused attention dots for head w (prescaled by log2 e)
  float ps[4][4], pd[4][4];              // [rg][r]
  #pragma unroll
  for(int rg=0;rg<4;rg++)
    #pragma unroll
    for(int r=0;r<4;r++){ ps[rg][r]=0.f; pd[rg][r]=0.f; }
  #pragma unroll
  for(int tt=0;tt<4;tt++){
    float sv = as1[w*64+tt*16+lo]*LOG2E, dv = ad1[w*64+tt*16+lo]*LOG2E;
    #pragma unroll
    for(int rg=0;rg<4;rg++)
      #pragma unroll
      for(int r=0;r<4;r++){ ps[rg][r] += acc[rg][tt][r]*sv; pd[rg][r] += acc[rg][tt][r]*dv; }
  }
  #pragma unroll
  for(int off=1; off<16; off<<=1){
    #pragma unroll
    for(int rg=0;rg<4;rg++)
      #pragma unroll
      for(int r=0;r<4;r++){
        ps[rg][r] += __shfl_xor(ps[rg][r], off, 64);
        pd[rg][r] += __shfl_xor(pd[rg][r], off, 64);
      }
  }
  if(lo == 0){
    #pragma unroll
    for(int rg=0;rg<4;rg++)
      #pragma unroll
      for(int r=0;r<4;r++){
        int row = rowbase + rg*16 + hi*4 + r;
        if(row < NN){ aS[row*HEADS+w] = ps[rg][r]; aD[row*HEADS+w] = pd[rg][r]; }
      }
  }
}

// ---- layer-1 aggregation + bias + BN + ELU -> h2 (f32), one wave per node (round-9 version).
__global__ __launch_bounds__(256) void k_agg1(const u16* __restrict__ h1b,
  const float* __restrict__ aS, const float* __restrict__ aD,
  const int* __restrict__ rowptr, const int* __restrict__ adj,
  const float* __restrict__ b1, const float* __restrict__ g1, const float* __restrict__ be1,
  const float* __restrict__ mn1, const float* __restrict__ vr1,
  float* __restrict__ h2){
  __shared__ float lw[4][CHUNK*4];   // [wave][i*4+head]
  __shared__ int   lsrc[4][CHUNK];
  int w = threadIdx.x >> 6, lane = threadIdx.x & 63;
  int node = blockIdx.x*4 + w;
  int h = lane >> 4;
  int beg = rowptr[node], end = rowptr[node+1];
  float4 ad4 = *(const float4*)&aD[node*HEADS];
  float den[4] = {0.f,0.f,0.f,0.f};
  float a0=0.f, a1=0.f, a2=0.f, a3=0.f;
  int total = end - beg + 1;                  // + self loop
  for(int c0=0; c0<total; c0+=CHUNK){
    int n = min(CHUNK, total - c0);
    for(int i=lane; i<n; i+=64){
      int e = beg + c0 + i;
      int src = (e < end) ? adj[e] : node;
      float4 s4 = *(const float4*)&aS[src*HEADS];
      float w0 = s4.x + ad4.x; w0 = w0>0.f?w0:SLOPE*w0; w0 = exp2f(fminf(w0,110.f));
      float w1 = s4.y + ad4.y; w1 = w1>0.f?w1:SLOPE*w1; w1 = exp2f(fminf(w1,110.f));
      float w2 = s4.z + ad4.z; w2 = w2>0.f?w2:SLOPE*w2; w2 = exp2f(fminf(w2,110.f));
      float w3 = s4.w + ad4.w; w3 = w3>0.f?w3:SLOPE*w3; w3 = exp2f(fminf(w3,110.f));
      lsrc[w][i] = src;
      *(float4*)&lw[w][i*4] = make_float4(w0,w1,w2,w3);
      den[0]+=w0; den[1]+=w1; den[2]+=w2; den[3]+=w3;
    }
    asm volatile("s_waitcnt lgkmcnt(0)" ::: "memory");
    #pragma unroll 2
    for(int i=0;i<n;i++){
      int s = lsrc[w][i];
      float wg = lw[w][i*4+h];
      ushort4 hv = *(const ushort4*)&h1b[(size_t)s*F1 + lane*4];
      a0 += wg*us2f(hv.x); a1 += wg*us2f(hv.y); a2 += wg*us2f(hv.z); a3 += wg*us2f(hv.w);
    }
  }
  #pragma unroll
  for(int off=1; off<64; off<<=1){
    #pragma unroll
    for(int q=0;q<4;q++) den[q] += __shfl_xor(den[q], off, 64);
  }
  float inv = 1.f/(den[h] + 1e-16f);
  int c = lane*4;
  float o[4] = {a0*inv, a1*inv, a2*inv, a3*inv};
  #pragma unroll
  for(int j=0;j<4;j++){
    float v = o[j] + b1[c+j];
    v = (v - mn1[c+j]) * rsqrtf(vr1[c+j] + 1e-5f) * g1[c+j] + be1[c+j];
    v = v > 0.f ? v : (__expf(v) - 1.f);            // ELU
    o[j] = v;
  }
  *(float4*)&h2[(size_t)node*F1 + c] = make_float4(o[0],o[1],o[2],o[3]);
}

// ---- GEMM2 (MFMA bf16x3, on-the-fly h2 split) + fused attention dots layer 2.
// Block: 64 rows, 4 waves; wave w: rows rowbase+w*16..+15, cols 0..47 (3 tiles, cols>=40 zero-padded).
__global__ __launch_bounds__(256) void k_gemm2(const float* __restrict__ h2,
    const short* __restrict__ w2h, const short* __restrict__ w2l,
    const float* __restrict__ as2, const float* __restrict__ ad2,
    float* __restrict__ h2p, float* __restrict__ aS2, float* __restrict__ aD2){
  int w = threadIdx.x >> 6, lane = threadIdx.x & 63;
  int lo = lane & 15, hi = lane >> 4;
  int rowbase = blockIdx.x*64 + w*16;
  int arow = rowbase + lo; if(arow >= NN) arow = NN-1;
  f32x4 acc[3];
  #pragma unroll
  for(int tt=0;tt<3;tt++) acc[tt] = (f32x4){0.f,0.f,0.f,0.f};
  const float* xp = h2 + (size_t)arow*F1 + 8*hi;
  const short* bph = w2h + (size_t)lo*F1 + 8*hi;
  const short* bpl = w2l + (size_t)lo*F1 + 8*hi;
  for(int k0=0; k0<F1; k0+=32){
    float4 va = *(const float4*)(xp + k0);
    float4 vb = *(const float4*)(xp + k0 + 4);
    float v[8] = {va.x,va.y,va.z,va.w,vb.x,vb.y,vb.z,vb.w};
    bf16x8 ah, al;
    #pragma unroll
    for(int j=0;j<8;j++){
      u32 u = __float_as_uint(v[j]);
      ah[j] = (short)(u >> 16);
      float hf = __uint_as_float(u & 0xffff0000u);
      al[j] = (short)(__float_as_uint(v[j] - hf) >> 16);
    }
    #pragma unroll
    for(int tt=0;tt<3;tt++){
      bf16x8 bh = *(const bf16x8*)(bph + (size_t)tt*16*F1 + k0);
      bf16x8 bl = *(const bf16x8*)(bpl + (size_t)tt*16*F1 + k0);
      acc[tt] = __builtin_amdgcn_mfma_f32_16x16x32_bf16(ah, bh, acc[tt], 0, 0, 0);
      acc[tt] = __builtin_amdgcn_mfma_f32_16x16x32_bf16(al, bh, acc[tt], 0, 0, 0);
      acc[tt] = __builtin_amdgcn_mfma_f32_16x16x32_bf16(ah, bl, acc[tt], 0, 0, 0);
    }
  }
  // stores + fused dots (prescaled by log2 e)
  float ps[4] = {0.f,0.f,0.f,0.f}, pd[4] = {0.f,0.f,0.f,0.f};
  #pragma unroll
  for(int tt=0;tt<3;tt++){
    int col = tt*16 + lo;
    float sv = (col < NC) ? as2[col]*LOG2E : 0.f;
    float dv = (col < NC) ? ad2[col]*LOG2E : 0.f;
    #pragma unroll
    for(int r=0;r<4;r++){
      int row = rowbase + hi*4 + r;
      if(row < NN && col < NC) h2p[(size_t)row*NC + col] = acc[tt][r];
      ps[r] += acc[tt][r]*sv; pd[r] += acc[tt][r]*dv;
    }
  }
  #pragma unroll
  for(int off=1; off<16; off<<=1){
    #pragma unroll
    for(int r=0;r<4;r++){ ps[r] += __shfl_xor(ps[r], off, 64); pd[r] += __shfl_xor(pd[r], off, 64); }
  }
  if(lo == 0){
    #pragma unroll
    for(int r=0;r<4;r++){
      int row = rowbase + hi*4 + r;
      if(row < NN){ aS2[row] = ps[r]; aD2[row] = pd[r]; }
    }
  }
}

// ---- layer-2 aggregation -> output (f32), no max pass, LDS weights
__global__ __launch_bounds__(256) void k_agg2(const float* __restrict__ h2p,
  const float* __restrict__ aS2, const float* __restrict__ aD2,
  const int* __restrict__ rowptr, const int* __restrict__ adj,
  const float* __restrict__ b2, float* __restrict__ out){
  __shared__ float lw[4][CHUNK];
  __shared__ int   lsrc[4][CHUNK];
  int w = threadIdx.x >> 6, lane = threadIdx.x & 63;
  int node = blockIdx.x*4 + w;
  int beg = rowptr[node], end = rowptr[node+1];
  float adv = aD2[node];
  float den = 0.f, acc = 0.f;
  int total = end - beg + 1;
  for(int c0=0; c0<total; c0+=CHUNK){
    int n = min(CHUNK, total - c0);
    for(int i=lane; i<n; i+=64){
      int e = beg + c0 + i;
      int src = (e < end) ? adj[e] : node;
      float ev = aS2[src] + adv; ev = ev>0.f?ev:SLOPE*ev;
      float wg = exp2f(fminf(ev,110.f));
      lsrc[w][i] = src;
      lw[w][i] = wg;
      den += wg;
    }
    asm volatile("s_waitcnt lgkmcnt(0)" ::: "memory");
    #pragma unroll 2
    for(int i=0;i<n;i++){
      int s = lsrc[w][i];
      float wg = lw[w][i];
      if(lane < NC) acc += wg * h2p[(size_t)s*NC + lane];
    }
  }
  #pragma unroll
  for(int off=1; off<64; off<<=1) den += __shfl_xor(den, off, 64);
  if(lane < NC) out[(size_t)node*NC + lane] = acc/(den + 1e-16f) + b2[lane];
}

extern "C" void kernel_launch(void* const* d_in, const int* in_sizes, int n_in,
                              void* d_out, int out_size, void* d_ws, size_t ws_size,
                              hipStream_t stream){
  (void)in_sizes; (void)n_in; (void)out_size; (void)ws_size;
  const float* x   = (const float*)d_in[0];
  const int*   ei  = (const int*)d_in[1];
  const float* W1  = (const float*)d_in[2];
  const float* as1 = (const float*)d_in[3];
  const float* ad1 = (const float*)d_in[4];
  const float* b1  = (const float*)d_in[5];
  const float* g1  = (const float*)d_in[6];
  const float* be1 = (const float*)d_in[7];
  const float* mn1 = (const float*)d_in[8];
  const float* vr1 = (const float*)d_in[9];
  const float* W2  = (const float*)d_in[10];
  const float* as2 = (const float*)d_in[11];
  const float* ad2 = (const float*)d_in[12];
  const float* b2  = (const float*)d_in[13];

  char* ws = (char*)d_ws;
  u16*  h1b    = (u16*) (ws + 0);             // 25,600,000 (bf16 h1)
  float* h2    = (float*)(ws + 25600000);     // 51,200,000
  // xh/xl alias h2 (dead once k_gemm1 completes; h2 written later by k_agg1)
  u16*  xh     = (u16*) (ws + 25600000);      // 25,600,000
  u16*  xl     = (u16*) (ws + 51200000);      // 25,600,000
  // w1h/w1l alias h2p (dead before k_gemm2 writes h2p)
  float* h2p   = (float*)(ws + 76800000);     //  8,000,000
  u16*  w1h    = (u16*) (ws + 76800000);      //    131,072
  u16*  w1l    = (u16*) (ws + 76931072);      //    131,072
  float* aS1   = (float*)(ws + 84800000);     //    800,000
  float* aD1   = (float*)(ws + 85600000);     //    800,000
  float* aS2   = (float*)(ws + 86400000);     //    200,000
  float* aD2   = (float*)(ws + 86600000);     //    200,000
  int*  rowptr = (int*)  (ws + 86800000);     //    200,016
  int*  adj    = (int*)  (ws + 87200016);     //  6,400,000
  u32*  bin    = (u32*)  (ws + 93700000);     //  7,056,000 (98*18000*4)
  int*  cnt    = (int*)  (ws + 100800000);    //        392 (98*4)
  int*  rloc   = (int*)  (ws + 100801024);    //    200,704 (98*512*4)
  int*  bsum   = (int*)  (ws + 101002240);    //        392
  int*  bbase  = (int*)  (ws + 101003264);    //        392
  u16*  w2h    = (u16*)  (ws + 101003712);    //     24,576 (48*256*2)
  u16*  w2l    = (u16*)  (ws + 101028288);    //     24,576

  hipMemsetAsync(cnt, 0, NB2*sizeof(int), stream);
  k_prep  <<<6554, 256, 0, stream>>>(x, xh, xl, W1, w1h, w1l, W2, w2h, w2l);
  k_bin   <<<(NE+TILE-1)/TILE, 256, 0, stream>>>(ei, cnt, bin);
  k_hist  <<<NB2, 256, 0, stream>>>(cnt, bin, rloc, bsum);
  k_scanb <<<1, 64, 0, stream>>>(bsum, bbase, rowptr);
  k_fill2 <<<NB2, 256, 0, stream>>>(cnt, bin, rloc, bbase, rowptr, adj);
  k_gemm1 <<<(NN+63)/64, 256, 0, stream>>>((const short*)xh, (const short*)xl,
                                           (const short*)w1h, (const short*)w1l,
                                           as1, ad1, h1b, aS1, aD1);
  k_agg1  <<<NN/4, 256, 0, stream>>>(h1b, aS1, aD1, rowptr, adj, b1, g1, be1, mn1, vr1, h2);
  k_gemm2 <<<(NN+63)/64, 256, 0, stream>>>(h2, (const short*)w2h, (const short*)w2l,
                                           as2, ad2, h2p, aS2, aD2);
  k_agg2  <<<NN/4, 256, 0, stream>>>(h2p, aS2, aD2, rowptr, adj, b2, (float*)d_out);
}